// Round 7
// baseline (121.722 us; speedup 1.0000x reference)
//
#include <hip/hip_runtime.h>
#include <hip/hip_fp16.h>
#include <math.h>

#define HWSZ 65536   // 256*256
#define IMGH 256
#define IMGW 256

typedef _Float16 half8 __attribute__((ext_vector_type(8)));
typedef float f32x4 __attribute__((ext_vector_type(4)));

__device__ inline unsigned short f2bf(float f) {
    unsigned u = __float_as_uint(f);
    return (unsigned short)((u + 0x7fffu + ((u >> 16) & 1u)) >> 16);
}
__device__ inline unsigned short f2h(float f) {
    __half h = __float2half(f);
    return __half_as_ushort(h);
}
__device__ inline __half2 duph2(unsigned s) {
    union { unsigned u; __half2 h; } c;
    c.u = (s & 0xffffu) * 0x10001u;
    return c.h;
}
__device__ inline void hacc(const uint4& q, __half2 w, __half2* v) {
    const __half2* h = (const __half2*)&q;
    v[0] = __hfma2(h[0], w, v[0]);
    v[1] = __hfma2(h[1], w, v[1]);
    v[2] = __hfma2(h[2], w, v[2]);
    v[3] = __hfma2(h[3], w, v[3]);
}

// ---------------- K0a: pack MFMA A-fragments (fp16) ----------------
__global__ void prep_weights(const float* __restrict__ w_off,
                             const float* __restrict__ w,
                             unsigned short* __restrict__ wApack,
                             unsigned short* __restrict__ wOffPack) {
    int i = blockIdx.x * 256 + threadIdx.x;
    if (i < 36864) {
        int e = i;
        int j = e & 7, lane = (e >> 3) & 63, kk = (e >> 9) & 1;
        int t2 = e >> 10;
        int tap = t2 % 9, g = t2 / 9;
        int o = g * 16 + (lane & 15);
        int c = kk * 32 + ((lane >> 4) & 3) * 8 + j;
        wApack[e] = f2h(w[(o * 64 + c) * 9 + tap]);
    } else if (i < 36864 + 18432) {
        int e = i - 36864;
        int j = e & 7, lane = (e >> 3) & 63, kk = (e >> 9) & 1;
        int t2 = e >> 10;
        int tap = t2 % 9, mt = t2 / 9;
        int d = mt * 16 + (lane & 15);
        int c = kk * 32 + ((lane >> 4) & 3) * 8 + j;
        float v = (d < 27) ? w_off[(d * 64 + c) * 9 + tap] : 0.f;
        wOffPack[e] = f2h(v);
    }
}

// ---------------- K0b: x NCHW fp32 -> NHWC fp16 ----------------
__global__ __launch_bounds__(256) void transpose_x(const float* __restrict__ x,
                                                   unsigned short* __restrict__ xT) {
    __shared__ float tile[64 * 65];
    int blk = blockIdx.x;              // 2048 = 2 * 1024
    int b = blk >> 10;
    int p0 = (blk & 1023) * 64;
    int t = threadIdx.x;
    const float* xb = x + (size_t)b * 64 * HWSZ;
    unsigned short* xTb = xT + (size_t)b * HWSZ * 64;
    int pp = t & 63;
    int c0r = t >> 6;
#pragma unroll
    for (int i = 0; i < 16; ++i) {
        int c = c0r + 4 * i;
        tile[c * 65 + pp] = xb[(size_t)c * HWSZ + p0 + pp];
    }
    __syncthreads();
#pragma unroll
    for (int it = 0; it < 2; ++it) {
        int item = t + it * 256;       // 512 items
        int p = item >> 3;
        int c0 = (item & 7) * 8;
        uint4 ow;
        ow.x = f2h(tile[(c0 + 0) * 65 + p]) | ((unsigned)f2h(tile[(c0 + 1) * 65 + p]) << 16);
        ow.y = f2h(tile[(c0 + 2) * 65 + p]) | ((unsigned)f2h(tile[(c0 + 3) * 65 + p]) << 16);
        ow.z = f2h(tile[(c0 + 4) * 65 + p]) | ((unsigned)f2h(tile[(c0 + 5) * 65 + p]) << 16);
        ow.w = f2h(tile[(c0 + 6) * 65 + p]) | ((unsigned)f2h(tile[(c0 + 7) * 65 + p]) << 16);
        *(uint4*)&xTb[(size_t)(p0 + p) * 64 + c0] = ow;
    }
}

// ---------------- K1: offset conv via MFMA (fp16) -> om[b][d][p] ----------------
__global__ __launch_bounds__(256) void offset_conv(const unsigned short* __restrict__ xT,
                                                   const unsigned short* __restrict__ wOffPack,
                                                   const float* __restrict__ b_off,
                                                   float* __restrict__ om) {
    __shared__ uint4 haloBuf[800];     // 10x10 cells x 64ch fp16, swizzled
    char* halo = (char*)haloBuf;
    int bid = blockIdx.x;              // 2048
    int blk = ((bid & 7) << 8) | (bid >> 3);   // XCD-chunked swizzle
    int b = blk >> 10;
    int tb = blk & 1023;
    int ty = tb >> 5, tx = tb & 31;
    int h0 = ty * 8, w0 = tx * 8;
    int t = threadIdx.x;
    const char* xbb = (const char*)(xT + (size_t)b * HWSZ * 64);

    for (int i = t; i < 800; i += 256) {
        int cell = i >> 3;
        int c0 = (i & 7) * 8;
        int r = cell / 10, s = cell - r * 10;
        int y = h0 - 1 + r, xx = w0 - 1 + s;
        uint4 v = {0u, 0u, 0u, 0u};
        if (y >= 0 && y < IMGH && xx >= 0 && xx < IMGW)
            v = *(const uint4*)(xbb + ((size_t)(y * IMGW + xx) << 7) + (c0 << 1));
        *(uint4*)(halo + (cell << 7) + (((c0 << 1)) ^ ((cell & 7) << 4))) = v;
    }
    __syncthreads();

    int lane = t & 63;
    int wid = __builtin_amdgcn_readfirstlane(t >> 6);
    int mt = wid & 1;
    int np = wid >> 1;
    f32x4 z = {0.f, 0.f, 0.f, 0.f};
    f32x4 acc[2] = {z, z};
    int lhi = lane >> 4;

    for (int tap = 0; tap < 9; ++tap) {
        const half8* ap = (const half8*)wOffPack;
        half8 a0 = ap[((mt * 9 + tap) * 2 + 0) * 64 + lane];
        half8 a1 = ap[((mt * 9 + tap) * 2 + 1) * 64 + lane];
        int dy = tap / 3, dx = tap - dy * 3;
#pragma unroll
        for (int nn = 0; nn < 2; ++nn) {
            int p = (np * 2 + nn) * 16 + (lane & 15);
            int cell = ((p >> 3) + dy) * 10 + (p & 7) + dx;
            int base = (cell << 7);
            int swz = (cell & 7) << 4;
            half8 b0 = *(const half8*)(halo + base + ((lhi << 4) ^ swz));
            acc[nn] = __builtin_amdgcn_mfma_f32_16x16x32_f16(a0, b0, acc[nn], 0, 0, 0);
            half8 b1 = *(const half8*)(halo + base + (((4 + lhi) << 4) ^ swz));
            acc[nn] = __builtin_amdgcn_mfma_f32_16x16x32_f16(a1, b1, acc[nn], 0, 0, 0);
        }
    }
    float* omb = om + (size_t)b * 27 * HWSZ;
#pragma unroll
    for (int nn = 0; nn < 2; ++nn) {
#pragma unroll
        for (int jj = 0; jj < 4; ++jj) {
            int d = mt * 16 + lhi * 4 + jj;
            if (d < 27) {
                int p = (np * 2 + nn) * 16 + (lane & 15);
                int gp = (h0 + (p >> 3)) * IMGW + w0 + (p & 7);
                omb[(size_t)d * HWSZ + gp] = acc[nn][jj] + b_off[d];
            }
        }
    }
}

// ---------------- K2: LDS-halo deformable sample + 3-stream pipelined MFMA ----------------
// Streams per tap t: A-frags(t+1) global prefetch; prm(t+2) LDS prefetch;
// q-corners(t+1) ds_reads interleaved inside hacc(t). MFMA(t) uses a_cur(t).
__global__ __launch_bounds__(256, 3) void dcn_main(const unsigned short* __restrict__ xT,
                                                   const float* __restrict__ om,
                                                   const unsigned short* __restrict__ wApack,
                                                   unsigned short* __restrict__ preout,
                                                   float* __restrict__ stats) {
    __shared__ uint4 haloBuf[2592];    // 324 cells x 128B = 41472 B
    __shared__ unsigned prmi[9][64];   // 2304 B
    __shared__ uint2 prmw[9][64];      // 4608 B (4 x fp16 weights)
    __shared__ float bstats[128];      // 512 B
    char* halo = (char*)haloBuf;
    int bid = blockIdx.x;              // 2048
    int blk = ((bid & 7) << 8) | (bid >> 3);   // XCD-chunked swizzle
    int b = blk >> 10;
    int tb = blk & 1023;
    int ty = tb >> 5, tx = tb & 31;
    int h0 = ty * 8, w0 = tx * 8;
    int t = threadIdx.x;
    const char* xbb = (const char*)(xT + (size_t)b * HWSZ * 64);
    const float* omb = om + (size_t)b * 27 * HWSZ;
    int lane = t & 63;
    int wid = t >> 6;
    int lp = lane & 15;
    int lhi = lane >> 4;
    int p = wid * 16 + lp;
    int hb = h0 - 5, wb = w0 - 5;

    if (t < 128) bstats[t] = 0.f;

    // stage halo: 324 cells x 8 chunks, chunk ch stored at slot ch^(cell&7)
    for (int i = t; i < 2592; i += 256) {
        int cell = i >> 3;
        int ch = i & 7;
        int r = cell / 18, c = cell - r * 18;
        int y = hb + r, xx = wb + c;
        uint4 v = {0u, 0u, 0u, 0u};
        if ((unsigned)y < 256u && (unsigned)xx < 256u)
            v = *(const uint4*)(xbb + ((size_t)((y << 8) + xx) << 7) + (ch << 4));
        *(uint4*)(halo + (cell << 7) + ((ch ^ (cell & 7)) << 4)) = v;
    }

    // bilinear params for all 9 taps
    for (int i = t; i < 576; i += 256) {
        int tap = i >> 6, pp = i & 63;
        int h = h0 + (pp >> 3), wc = w0 + (pp & 7);
        int gp = h * IMGW + wc;
        float offy = omb[(size_t)tap * HWSZ + gp];
        float offx = omb[(size_t)(tap + 9) * HWSZ + gp];
        float mraw = omb[(size_t)(tap + 18) * HWSZ + gp];
        float m = 1.f / (1.f + __expf(-mraw));
        float pyf = (float)(h + tap / 3 - 1) + offy;
        float pxf = (float)(wc + tap % 3 - 1) + offx;
        float y0f = floorf(pyf), x0f = floorf(pxf);
        float wy = pyf - y0f, wx = pxf - x0f;
        int y0 = (int)y0f, x0 = (int)x0f;
        int y1 = y0 + 1, x1 = x0 + 1;
        float vy0 = (y0 >= 0 && y0 < IMGH) ? 1.f : 0.f;
        float vy1 = (y1 >= 0 && y1 < IMGH) ? 1.f : 0.f;
        float vx0 = (x0 >= 0 && x0 < IMGW) ? 1.f : 0.f;
        float vx1 = (x1 >= 0 && x1 < IMGW) ? 1.f : 0.f;
        float w00 = (1.f - wy) * (1.f - wx) * m * vy0 * vx0;
        float w01 = (1.f - wy) * wx * m * vy0 * vx1;
        float w10 = wy * (1.f - wx) * m * vy1 * vx0;
        float w11 = wy * wx * m * vy1 * vx1;
        prmw[tap][pp] = make_uint2((unsigned)f2h(w00) | ((unsigned)f2h(w01) << 16),
                                   (unsigned)f2h(w10) | ((unsigned)f2h(w11) << 16));
        int ry0 = y0 - hb, rx0 = x0 - wb;
        unsigned enc;
        if ((unsigned)ry0 <= 16u && (unsigned)rx0 <= 16u) {
            enc = (unsigned)((ry0 * 18 + rx0) << 7);            // bit0 = 0
        } else {
            int y0s = min(max(y0, -8), 383) + 8;                // 9 bits
            int x0s = min(max(x0, -8), 383) + 8;
            enc = 1u | ((unsigned)y0s << 1) | ((unsigned)x0s << 10);
        }
        prmi[tap][pp] = enc;
    }
    __syncthreads();
    // ---- main loop: waves independent, zero barriers ----

    f32x4 z = {0.f, 0.f, 0.f, 0.f};
    f32x4 acc[4] = {z, z, z, z};
    const half8* ap = (const half8*)wApack;
    uint4 q[4][2];                     // [corner][kk]
    half8 a_cur[8], a_nxt[8];

#define LOADC_H1(PI)                                                          \
    {                                                                         \
        unsigned pi_ = (PI);                                                  \
        bool fb_ = (pi_ & 1u);                                                \
        unsigned base_ = fb_ ? 0u : pi_;                                      \
        unsigned o00 = base_, o01 = base_ + 128u;                             \
        q[0][0] = *(const uint4*)(halo + o00 + ((lhi ^ ((o00 >> 7) & 7)) << 4));       \
        q[0][1] = *(const uint4*)(halo + o00 + (((4 + lhi) ^ ((o00 >> 7) & 7)) << 4)); \
        q[1][0] = *(const uint4*)(halo + o01 + ((lhi ^ ((o01 >> 7) & 7)) << 4));       \
        q[1][1] = *(const uint4*)(halo + o01 + (((4 + lhi) ^ ((o01 >> 7) & 7)) << 4)); \
        if (__ballot(fb_)) {                                                  \
            if (fb_) {                                                        \
                int y0r = (int)((pi_ >> 1) & 511) - 8;                        \
                int x0r = (int)((pi_ >> 10) & 511) - 8;                       \
                int y0c = min(max(y0r, 0), 255);                              \
                int x0c = min(max(x0r, 0), 255), x1c = min(max(x0r + 1, 0), 255); \
                const char* g00 = xbb + (((y0c << 8) + x0c) << 7) + (lhi << 4); \
                const char* g01 = xbb + (((y0c << 8) + x1c) << 7) + (lhi << 4); \
                q[0][0] = *(const uint4*)g00; q[0][1] = *(const uint4*)(g00 + 64); \
                q[1][0] = *(const uint4*)g01; q[1][1] = *(const uint4*)(g01 + 64); \
            }                                                                 \
        }                                                                     \
    }

#define LOADC_H2(PI)                                                          \
    {                                                                         \
        unsigned pi_ = (PI);                                                  \
        bool fb_ = (pi_ & 1u);                                                \
        unsigned base_ = fb_ ? 0u : pi_;                                      \
        unsigned o10 = base_ + 2304u, o11 = base_ + 2432u;                    \
        q[2][0] = *(const uint4*)(halo + o10 + ((lhi ^ ((o10 >> 7) & 7)) << 4));       \
        q[2][1] = *(const uint4*)(halo + o10 + (((4 + lhi) ^ ((o10 >> 7) & 7)) << 4)); \
        q[3][0] = *(const uint4*)(halo + o11 + ((lhi ^ ((o11 >> 7) & 7)) << 4));       \
        q[3][1] = *(const uint4*)(halo + o11 + (((4 + lhi) ^ ((o11 >> 7) & 7)) << 4)); \
        if (__ballot(fb_)) {                                                  \
            if (fb_) {                                                        \
                int y0r = (int)((pi_ >> 1) & 511) - 8;                        \
                int x0r = (int)((pi_ >> 10) & 511) - 8;                       \
                int y1c = min(max(y0r + 1, 0), 255);                          \
                int x0c = min(max(x0r, 0), 255), x1c = min(max(x0r + 1, 0), 255); \
                const char* g10 = xbb + (((y1c << 8) + x0c) << 7) + (lhi << 4); \
                const char* g11 = xbb + (((y1c << 8) + x1c) << 7) + (lhi << 4); \
                q[2][0] = *(const uint4*)g10; q[2][1] = *(const uint4*)(g10 + 64); \
                q[3][0] = *(const uint4*)g11; q[3][1] = *(const uint4*)(g11 + 64); \
            }                                                                 \
        }                                                                     \
    }

    // prologue: prm(0),prm(1); A(0); q(0)
    unsigned pi_c = prmi[0][p], pi_n = prmi[1][p];
    uint2 ww_c = prmw[0][p], ww_n = prmw[1][p];
#pragma unroll
    for (int u = 0; u < 8; ++u)
        a_cur[u] = ap[(((u >> 1) * 9 + 0) * 2 + (u & 1)) * 64 + lane];
    LOADC_H1(pi_c);
    LOADC_H2(pi_c);

#pragma unroll
    for (int tap = 0; tap < 9; ++tap) {
        // stream 1: A-fragments for tap+1 (global, consumed next tap)
        if (tap < 8) {
#pragma unroll
            for (int u = 0; u < 8; ++u)
                a_nxt[u] = ap[(((u >> 1) * 9 + (tap + 1)) * 2 + (u & 1)) * 64 + lane];
        }
        __half2 W00 = duph2(ww_c.x), W01 = duph2(ww_c.x >> 16);
        __half2 W10 = duph2(ww_c.y), W11 = duph2(ww_c.y >> 16);
        union HV { __half2 h2[4]; half8 h8; } V0, V1;
        __half2 z2 = __float2half2_rn(0.f);
#pragma unroll
        for (int j = 0; j < 4; ++j) { V0.h2[j] = z2; V1.h2[j] = z2; }
        // consume corners 00/01, then immediately reload them for tap+1
        hacc(q[0][0], W00, V0.h2); hacc(q[0][1], W00, V1.h2);
        hacc(q[1][0], W01, V0.h2); hacc(q[1][1], W01, V1.h2);
        if (tap < 8) LOADC_H1(pi_n);
        hacc(q[2][0], W10, V0.h2); hacc(q[2][1], W10, V1.h2);
        hacc(q[3][0], W11, V0.h2); hacc(q[3][1], W11, V1.h2);
        if (tap < 8) LOADC_H2(pi_n);
        half8 b0 = V0.h8, b1 = V1.h8;
        // stream 2: prm for tap+2 (LDS, issued after q so q waits don't cover it)
        unsigned pi_t = pi_n;
        uint2 ww_t = ww_n;
        if (tap < 7) { pi_n = prmi[tap + 2][p]; ww_n = prmw[tap + 2][p]; }
        __builtin_amdgcn_s_setprio(1);
#pragma unroll
        for (int g2 = 0; g2 < 4; ++g2) {
            acc[g2] = __builtin_amdgcn_mfma_f32_16x16x32_f16(a_cur[g2 * 2 + 0], b0, acc[g2], 0, 0, 0);
            acc[g2] = __builtin_amdgcn_mfma_f32_16x16x32_f16(a_cur[g2 * 2 + 1], b1, acc[g2], 0, 0, 0);
        }
        __builtin_amdgcn_s_setprio(0);
        pi_c = pi_t; ww_c = ww_t;
#pragma unroll
        for (int u = 0; u < 8; ++u) a_cur[u] = a_nxt[u];   // SSA-renamed, no movs after unroll
    }
#undef LOADC_H1
#undef LOADC_H2

    // epilogue: preout (bf16, NCHW)
    unsigned short* pob = preout + (size_t)b * 64 * HWSZ;
    int gp = (h0 + (p >> 3)) * IMGW + w0 + (p & 7);
#pragma unroll
    for (int g2 = 0; g2 < 4; ++g2) {
#pragma unroll
        for (int jj = 0; jj < 4; ++jj) {
            int o = g2 * 16 + lhi * 4 + jj;
            pob[(size_t)o * HWSZ + gp] = f2bf(acc[g2][jj]);
        }
    }
    // BN partial stats
#pragma unroll
    for (int g2 = 0; g2 < 4; ++g2) {
#pragma unroll
        for (int jj = 0; jj < 4; ++jj) {
            float s1 = acc[g2][jj];
            float s2 = s1 * s1;
#pragma unroll
            for (int mask = 1; mask < 16; mask <<= 1) {
                s1 += __shfl_xor(s1, mask);
                s2 += __shfl_xor(s2, mask);
            }
            if (lp == 0) {
                int o = g2 * 16 + lhi * 4 + jj;
                atomicAdd(&bstats[o], s1);
                atomicAdd(&bstats[64 + o], s2);
            }
        }
    }
    __syncthreads();
    if (t < 128) atomicAdd(&stats[t], bstats[t]);
}

// ---------------- K3: normalize + relu + residual ----------------
__global__ __launch_bounds__(256) void bn_finalize(const float* __restrict__ stats,
                                                   const float* __restrict__ gamma,
                                                   const float* __restrict__ beta,
                                                   const float* __restrict__ x,
                                                   const unsigned short* __restrict__ preout,
                                                   float* __restrict__ out) {
    int i = blockIdx.x * 256 + threadIdx.x;     // uint4 idx over 8.4M bf16
    int e0 = i * 8;
    int o = (e0 >> 16) & 63;
    const float inv_n = 1.f / 131072.f;
    float mean = stats[o] * inv_n;
    float var = stats[64 + o] * inv_n - mean * mean;
    float rstd = rsqrtf(var + 1e-5f);
    float g = gamma[o] * rstd;
    float bb = beta[o] - mean * g;
    uint4 q = ((const uint4*)preout)[i];
    float4 x0 = ((const float4*)x)[i * 2];
    float4 x1 = ((const float4*)x)[i * 2 + 1];
    float4 r0, r1;
    r0.x = fmaxf(__uint_as_float(q.x << 16) * g + bb, 0.f) + x0.x;
    r0.y = fmaxf(__uint_as_float(q.x & 0xffff0000u) * g + bb, 0.f) + x0.y;
    r0.z = fmaxf(__uint_as_float(q.y << 16) * g + bb, 0.f) + x0.z;
    r0.w = fmaxf(__uint_as_float(q.y & 0xffff0000u) * g + bb, 0.f) + x0.w;
    r1.x = fmaxf(__uint_as_float(q.z << 16) * g + bb, 0.f) + x1.x;
    r1.y = fmaxf(__uint_as_float(q.z & 0xffff0000u) * g + bb, 0.f) + x1.y;
    r1.z = fmaxf(__uint_as_float(q.w << 16) * g + bb, 0.f) + x1.z;
    r1.w = fmaxf(__uint_as_float(q.w & 0xffff0000u) * g + bb, 0.f) + x1.w;
    ((float4*)out)[i * 2] = r0;
    ((float4*)out)[i * 2 + 1] = r1;
}

extern "C" void kernel_launch(void* const* d_in, const int* in_sizes, int n_in,
                              void* d_out, int out_size, void* d_ws, size_t ws_size,
                              hipStream_t stream) {
    const float* x     = (const float*)d_in[0];
    const float* w_off = (const float*)d_in[1];
    const float* b_off = (const float*)d_in[2];
    const float* w     = (const float*)d_in[3];
    const float* gamma = (const float*)d_in[5];
    const float* beta  = (const float*)d_in[6];
    float* out = (float*)d_out;
    char* wsb = (char*)d_ws;

    unsigned short* xT       = (unsigned short*)wsb;                    // 16,777,216 B (fp16)
    float*          om       = (float*)(wsb + 16777216);                // 14,155,776 B
    unsigned short* preout   = (unsigned short*)(wsb + 30932992);       // 16,777,216 B (bf16)
    unsigned short* wApack   = (unsigned short*)(wsb + 47710208);       // 73,728 B (fp16)
    unsigned short* wOffPack = (unsigned short*)(wsb + 47783936);       // 36,864 B (fp16)
    float*          stats    = (float*)(wsb + 47820800);                // 512 B

    hipMemsetAsync(stats, 0, 512, stream);
    prep_weights<<<216, 256, 0, stream>>>(w_off, w, wApack, wOffPack);
    transpose_x<<<2048, 256, 0, stream>>>(x, xT);
    offset_conv<<<2048, 256, 0, stream>>>(xT, wOffPack, b_off, om);
    dcn_main<<<2048, 256, 0, stream>>>(xT, om, wApack, preout, stats);
    bn_finalize<<<4096, 256, 0, stream>>>(stats, gamma, beta, x, preout, out);
}

// Round 8
// 101.584 us; speedup vs baseline: 1.1982x; 1.1982x over previous
//
#include <hip/hip_runtime.h>
#include <hip/hip_fp16.h>
#include <math.h>

#define HWSZ 65536   // 256*256
#define IMGH 256
#define IMGW 256

typedef _Float16 half8 __attribute__((ext_vector_type(8)));
typedef float f32x4 __attribute__((ext_vector_type(4)));

__device__ inline unsigned short f2bf(float f) {
    unsigned u = __float_as_uint(f);
    return (unsigned short)((u + 0x7fffu + ((u >> 16) & 1u)) >> 16);
}
__device__ inline unsigned short f2h(float f) {
    __half h = __float2half(f);
    return __half_as_ushort(h);
}
__device__ inline __half2 duph2(unsigned s) {
    union { unsigned u; __half2 h; } c;
    c.u = (s & 0xffffu) * 0x10001u;
    return c.h;
}
__device__ inline void hacc(const uint4& q, __half2 w, __half2* v) {
    const __half2* h = (const __half2*)&q;
    v[0] = __hfma2(h[0], w, v[0]);
    v[1] = __hfma2(h[1], w, v[1]);
    v[2] = __hfma2(h[2], w, v[2]);
    v[3] = __hfma2(h[3], w, v[3]);
}

// ---------------- K0a: pack MFMA A-fragments (fp16) ----------------
__global__ void prep_weights(const float* __restrict__ w_off,
                             const float* __restrict__ w,
                             unsigned short* __restrict__ wApack,
                             unsigned short* __restrict__ wOffPack) {
    int i = blockIdx.x * 256 + threadIdx.x;
    if (i < 36864) {
        int e = i;
        int j = e & 7, lane = (e >> 3) & 63, kk = (e >> 9) & 1;
        int t2 = e >> 10;
        int tap = t2 % 9, g = t2 / 9;
        int o = g * 16 + (lane & 15);
        int c = kk * 32 + ((lane >> 4) & 3) * 8 + j;
        wApack[e] = f2h(w[(o * 64 + c) * 9 + tap]);
    } else if (i < 36864 + 18432) {
        int e = i - 36864;
        int j = e & 7, lane = (e >> 3) & 63, kk = (e >> 9) & 1;
        int t2 = e >> 10;
        int tap = t2 % 9, mt = t2 / 9;
        int d = mt * 16 + (lane & 15);
        int c = kk * 32 + ((lane >> 4) & 3) * 8 + j;
        float v = (d < 27) ? w_off[(d * 64 + c) * 9 + tap] : 0.f;
        wOffPack[e] = f2h(v);
    }
}

// ---------------- K0b: x NCHW fp32 -> NHWC fp16 ----------------
__global__ __launch_bounds__(256) void transpose_x(const float* __restrict__ x,
                                                   unsigned short* __restrict__ xT) {
    __shared__ float tile[64 * 65];
    int blk = blockIdx.x;              // 2048 = 2 * 1024
    int b = blk >> 10;
    int p0 = (blk & 1023) * 64;
    int t = threadIdx.x;
    const float* xb = x + (size_t)b * 64 * HWSZ;
    unsigned short* xTb = xT + (size_t)b * HWSZ * 64;
    int pp = t & 63;
    int c0r = t >> 6;
#pragma unroll
    for (int i = 0; i < 16; ++i) {
        int c = c0r + 4 * i;
        tile[c * 65 + pp] = xb[(size_t)c * HWSZ + p0 + pp];
    }
    __syncthreads();
#pragma unroll
    for (int it = 0; it < 2; ++it) {
        int item = t + it * 256;       // 512 items
        int p = item >> 3;
        int c0 = (item & 7) * 8;
        uint4 ow;
        ow.x = f2h(tile[(c0 + 0) * 65 + p]) | ((unsigned)f2h(tile[(c0 + 1) * 65 + p]) << 16);
        ow.y = f2h(tile[(c0 + 2) * 65 + p]) | ((unsigned)f2h(tile[(c0 + 3) * 65 + p]) << 16);
        ow.z = f2h(tile[(c0 + 4) * 65 + p]) | ((unsigned)f2h(tile[(c0 + 5) * 65 + p]) << 16);
        ow.w = f2h(tile[(c0 + 6) * 65 + p]) | ((unsigned)f2h(tile[(c0 + 7) * 65 + p]) << 16);
        *(uint4*)&xTb[(size_t)(p0 + p) * 64 + c0] = ow;
    }
}

// ---------------- K1: offset conv via MFMA (fp16) -> om[b][d][p] ----------------
__global__ __launch_bounds__(256) void offset_conv(const unsigned short* __restrict__ xT,
                                                   const unsigned short* __restrict__ wOffPack,
                                                   const float* __restrict__ b_off,
                                                   float* __restrict__ om) {
    __shared__ uint4 haloBuf[800];     // 10x10 cells x 64ch fp16, swizzled
    char* halo = (char*)haloBuf;
    int bid = blockIdx.x;              // 2048
    int blk = ((bid & 7) << 8) | (bid >> 3);   // XCD-chunked swizzle
    int b = blk >> 10;
    int tb = blk & 1023;
    int ty = tb >> 5, tx = tb & 31;
    int h0 = ty * 8, w0 = tx * 8;
    int t = threadIdx.x;
    const char* xbb = (const char*)(xT + (size_t)b * HWSZ * 64);

    for (int i = t; i < 800; i += 256) {
        int cell = i >> 3;
        int c0 = (i & 7) * 8;
        int r = cell / 10, s = cell - r * 10;
        int y = h0 - 1 + r, xx = w0 - 1 + s;
        uint4 v = {0u, 0u, 0u, 0u};
        if (y >= 0 && y < IMGH && xx >= 0 && xx < IMGW)
            v = *(const uint4*)(xbb + ((size_t)(y * IMGW + xx) << 7) + (c0 << 1));
        *(uint4*)(halo + (cell << 7) + (((c0 << 1)) ^ ((cell & 7) << 4))) = v;
    }
    __syncthreads();

    int lane = t & 63;
    int wid = __builtin_amdgcn_readfirstlane(t >> 6);
    int mt = wid & 1;
    int np = wid >> 1;
    f32x4 z = {0.f, 0.f, 0.f, 0.f};
    f32x4 acc[2] = {z, z};
    int lhi = lane >> 4;

    for (int tap = 0; tap < 9; ++tap) {
        const half8* ap = (const half8*)wOffPack;
        half8 a0 = ap[((mt * 9 + tap) * 2 + 0) * 64 + lane];
        half8 a1 = ap[((mt * 9 + tap) * 2 + 1) * 64 + lane];
        int dy = tap / 3, dx = tap - dy * 3;
#pragma unroll
        for (int nn = 0; nn < 2; ++nn) {
            int p = (np * 2 + nn) * 16 + (lane & 15);
            int cell = ((p >> 3) + dy) * 10 + (p & 7) + dx;
            int base = (cell << 7);
            int swz = (cell & 7) << 4;
            half8 b0 = *(const half8*)(halo + base + ((lhi << 4) ^ swz));
            acc[nn] = __builtin_amdgcn_mfma_f32_16x16x32_f16(a0, b0, acc[nn], 0, 0, 0);
            half8 b1 = *(const half8*)(halo + base + (((4 + lhi) << 4) ^ swz));
            acc[nn] = __builtin_amdgcn_mfma_f32_16x16x32_f16(a1, b1, acc[nn], 0, 0, 0);
        }
    }
    float* omb = om + (size_t)b * 27 * HWSZ;
#pragma unroll
    for (int nn = 0; nn < 2; ++nn) {
#pragma unroll
        for (int jj = 0; jj < 4; ++jj) {
            int d = mt * 16 + lhi * 4 + jj;
            if (d < 27) {
                int p = (np * 2 + nn) * 16 + (lane & 15);
                int gp = (h0 + (p >> 3)) * IMGW + w0 + (p & 7);
                omb[(size_t)d * HWSZ + gp] = acc[nn][jj] + b_off[d];
            }
        }
    }
}

// ---------------- K2: 512-thread 16x8-tile LDS-halo deformable sample + MFMA ----------------
// Halo 26x18 cells x 64ch fp16 (rows h0-5..h0+20, cols w0-5..w0+12), chunk-XOR
// swizzled. 8 waves x 16px x 64 och. 2 blocks/CU target (74.2 KB LDS).
__global__ __launch_bounds__(512, 4) void dcn_main(const unsigned short* __restrict__ xT,
                                                   const float* __restrict__ om,
                                                   const unsigned short* __restrict__ wApack,
                                                   unsigned short* __restrict__ preout,
                                                   float* __restrict__ stats) {
    __shared__ uint4 haloBuf[3744];    // 468 cells x 128B = 59904 B
    __shared__ unsigned prmi[9][128];  // 4608 B
    __shared__ uint2 prmw[9][128];     // 9216 B
    __shared__ float bstats[128];      // 512 B
    char* halo = (char*)haloBuf;
    int bid = blockIdx.x;              // 1024
    int blk = ((bid & 7) << 7) | (bid >> 3);   // XCD-chunked swizzle (1024%8==0)
    int b = blk >> 9;
    int tb = blk & 511;                // 512 tiles/batch = 16 row-tiles x 32 col-tiles
    int ty = tb >> 5, tx = tb & 31;
    int h0 = ty * 16, w0 = tx * 8;
    int t = threadIdx.x;
    const char* xbb = (const char*)(xT + (size_t)b * HWSZ * 64);
    const float* omb = om + (size_t)b * 27 * HWSZ;
    int lane = t & 63;
    int wid = t >> 6;                  // 0..7
    int lp = lane & 15;
    int lhi = lane >> 4;
    int p = wid * 16 + lp;             // 0..127 ; pixel (p>>3, p&7) in 16x8 tile
    int hb = h0 - 5, wb = w0 - 5;

    if (t < 128) bstats[t] = 0.f;

    // stage halo: 468 cells x 8 chunks, chunk ch stored at slot ch^(cell&7)
    for (int i = t; i < 3744; i += 512) {
        int cell = i >> 3;
        int ch = i & 7;
        int r = cell / 18, c = cell - r * 18;
        int y = hb + r, xx = wb + c;
        uint4 v = {0u, 0u, 0u, 0u};
        if ((unsigned)y < 256u && (unsigned)xx < 256u)
            v = *(const uint4*)(xbb + ((size_t)((y << 8) + xx) << 7) + (ch << 4));
        *(uint4*)(halo + (cell << 7) + ((ch ^ (cell & 7)) << 4)) = v;
    }

    // bilinear params for all 9 taps x 128 px
    for (int i = t; i < 1152; i += 512) {
        int tap = i >> 7, pp = i & 127;
        int h = h0 + (pp >> 3), wc = w0 + (pp & 7);
        int gp = h * IMGW + wc;
        float offy = omb[(size_t)tap * HWSZ + gp];
        float offx = omb[(size_t)(tap + 9) * HWSZ + gp];
        float mraw = omb[(size_t)(tap + 18) * HWSZ + gp];
        float m = 1.f / (1.f + __expf(-mraw));
        float pyf = (float)(h + tap / 3 - 1) + offy;
        float pxf = (float)(wc + tap % 3 - 1) + offx;
        float y0f = floorf(pyf), x0f = floorf(pxf);
        float wy = pyf - y0f, wx = pxf - x0f;
        int y0 = (int)y0f, x0 = (int)x0f;
        int y1 = y0 + 1, x1 = x0 + 1;
        float vy0 = (y0 >= 0 && y0 < IMGH) ? 1.f : 0.f;
        float vy1 = (y1 >= 0 && y1 < IMGH) ? 1.f : 0.f;
        float vx0 = (x0 >= 0 && x0 < IMGW) ? 1.f : 0.f;
        float vx1 = (x1 >= 0 && x1 < IMGW) ? 1.f : 0.f;
        float w00 = (1.f - wy) * (1.f - wx) * m * vy0 * vx0;
        float w01 = (1.f - wy) * wx * m * vy0 * vx1;
        float w10 = wy * (1.f - wx) * m * vy1 * vx0;
        float w11 = wy * wx * m * vy1 * vx1;
        prmw[tap][pp] = make_uint2((unsigned)f2h(w00) | ((unsigned)f2h(w01) << 16),
                                   (unsigned)f2h(w10) | ((unsigned)f2h(w11) << 16));
        int ry0 = y0 - hb, rx0 = x0 - wb;
        unsigned enc;
        if ((unsigned)ry0 <= 24u && (unsigned)rx0 <= 16u) {
            enc = (unsigned)((ry0 * 18 + rx0) << 7);            // bit0 = 0
        } else {
            int y0s = min(max(y0, -8), 383) + 8;                // 9 bits
            int x0s = min(max(x0, -8), 383) + 8;
            enc = 1u | ((unsigned)y0s << 1) | ((unsigned)x0s << 10);
        }
        prmi[tap][pp] = enc;
    }
    __syncthreads();
    // ---- main loop: waves independent, zero barriers ----

    f32x4 z = {0.f, 0.f, 0.f, 0.f};
    f32x4 acc[4] = {z, z, z, z};
    const half8* ap = (const half8*)wApack;
    uint4 q[4][2];                     // [corner][kk]

#define LOADC(PI)                                                             \
    {                                                                         \
        unsigned pi_ = (PI);                                                  \
        bool fb_ = (pi_ & 1u);                                                \
        unsigned base_ = fb_ ? 0u : pi_;                                      \
        unsigned o00 = base_, o01 = base_ + 128u,                             \
                 o10 = base_ + 2304u, o11 = base_ + 2432u;                    \
        q[0][0] = *(const uint4*)(halo + o00 + ((lhi ^ ((o00 >> 7) & 7)) << 4));       \
        q[0][1] = *(const uint4*)(halo + o00 + (((4 + lhi) ^ ((o00 >> 7) & 7)) << 4)); \
        q[1][0] = *(const uint4*)(halo + o01 + ((lhi ^ ((o01 >> 7) & 7)) << 4));       \
        q[1][1] = *(const uint4*)(halo + o01 + (((4 + lhi) ^ ((o01 >> 7) & 7)) << 4)); \
        q[2][0] = *(const uint4*)(halo + o10 + ((lhi ^ ((o10 >> 7) & 7)) << 4));       \
        q[2][1] = *(const uint4*)(halo + o10 + (((4 + lhi) ^ ((o10 >> 7) & 7)) << 4)); \
        q[3][0] = *(const uint4*)(halo + o11 + ((lhi ^ ((o11 >> 7) & 7)) << 4));       \
        q[3][1] = *(const uint4*)(halo + o11 + (((4 + lhi) ^ ((o11 >> 7) & 7)) << 4)); \
        if (__ballot(fb_)) {                                                  \
            if (fb_) {                                                        \
                int y0r = (int)((pi_ >> 1) & 511) - 8;                        \
                int x0r = (int)((pi_ >> 10) & 511) - 8;                       \
                int y0c = min(max(y0r, 0), 255), y1c = min(max(y0r + 1, 0), 255); \
                int x0c = min(max(x0r, 0), 255), x1c = min(max(x0r + 1, 0), 255); \
                const char* g00 = xbb + (((y0c << 8) + x0c) << 7) + (lhi << 4); \
                const char* g01 = xbb + (((y0c << 8) + x1c) << 7) + (lhi << 4); \
                const char* g10 = xbb + (((y1c << 8) + x0c) << 7) + (lhi << 4); \
                const char* g11 = xbb + (((y1c << 8) + x1c) << 7) + (lhi << 4); \
                q[0][0] = *(const uint4*)g00; q[0][1] = *(const uint4*)(g00 + 64); \
                q[1][0] = *(const uint4*)g01; q[1][1] = *(const uint4*)(g01 + 64); \
                q[2][0] = *(const uint4*)g10; q[2][1] = *(const uint4*)(g10 + 64); \
                q[3][0] = *(const uint4*)g11; q[3][1] = *(const uint4*)(g11 + 64); \
            }                                                                 \
        }                                                                     \
    }

    unsigned pi = prmi[0][p];
    uint2 ww = prmw[0][p];
    LOADC(pi);

#pragma unroll
    for (int tap = 0; tap < 9; ++tap) {
        __half2 W00 = duph2(ww.x), W01 = duph2(ww.x >> 16);
        __half2 W10 = duph2(ww.y), W11 = duph2(ww.y >> 16);
        union HV { __half2 h2[4]; half8 h8; } V0, V1;
        __half2 z2 = __float2half2_rn(0.f);
#pragma unroll
        for (int j = 0; j < 4; ++j) { V0.h2[j] = z2; V1.h2[j] = z2; }
        hacc(q[0][0], W00, V0.h2); hacc(q[0][1], W00, V1.h2);
        hacc(q[1][0], W01, V0.h2); hacc(q[1][1], W01, V1.h2);
        hacc(q[2][0], W10, V0.h2); hacc(q[2][1], W10, V1.h2);
        hacc(q[3][0], W11, V0.h2); hacc(q[3][1], W11, V1.h2);
        half8 b0 = V0.h8, b1 = V1.h8;
        if (tap < 8) {                 // prefetch next tap's corners
            pi = prmi[tap + 1][p];
            ww = prmw[tap + 1][p];
            LOADC(pi);
        }
        __builtin_amdgcn_s_setprio(1);
#pragma unroll
        for (int g2 = 0; g2 < 4; ++g2) {
            half8 a0 = ap[((g2 * 9 + tap) * 2 + 0) * 64 + lane];
            half8 a1 = ap[((g2 * 9 + tap) * 2 + 1) * 64 + lane];
            acc[g2] = __builtin_amdgcn_mfma_f32_16x16x32_f16(a0, b0, acc[g2], 0, 0, 0);
            acc[g2] = __builtin_amdgcn_mfma_f32_16x16x32_f16(a1, b1, acc[g2], 0, 0, 0);
        }
        __builtin_amdgcn_s_setprio(0);
    }
#undef LOADC

    // epilogue: preout (bf16, NCHW)
    unsigned short* pob = preout + (size_t)b * 64 * HWSZ;
    int gp = (h0 + (p >> 3)) * IMGW + w0 + (p & 7);
#pragma unroll
    for (int g2 = 0; g2 < 4; ++g2) {
#pragma unroll
        for (int jj = 0; jj < 4; ++jj) {
            int o = g2 * 16 + lhi * 4 + jj;
            pob[(size_t)o * HWSZ + gp] = f2bf(acc[g2][jj]);
        }
    }
    // BN partial stats
#pragma unroll
    for (int g2 = 0; g2 < 4; ++g2) {
#pragma unroll
        for (int jj = 0; jj < 4; ++jj) {
            float s1 = acc[g2][jj];
            float s2 = s1 * s1;
#pragma unroll
            for (int mask = 1; mask < 16; mask <<= 1) {
                s1 += __shfl_xor(s1, mask);
                s2 += __shfl_xor(s2, mask);
            }
            if (lp == 0) {
                int o = g2 * 16 + lhi * 4 + jj;
                atomicAdd(&bstats[o], s1);
                atomicAdd(&bstats[64 + o], s2);
            }
        }
    }
    __syncthreads();
    if (t < 128) atomicAdd(&stats[t], bstats[t]);
}

// ---------------- K3: normalize + relu + residual ----------------
__global__ __launch_bounds__(256) void bn_finalize(const float* __restrict__ stats,
                                                   const float* __restrict__ gamma,
                                                   const float* __restrict__ beta,
                                                   const float* __restrict__ x,
                                                   const unsigned short* __restrict__ preout,
                                                   float* __restrict__ out) {
    int i = blockIdx.x * 256 + threadIdx.x;     // uint4 idx over 8.4M bf16
    int e0 = i * 8;
    int o = (e0 >> 16) & 63;
    const float inv_n = 1.f / 131072.f;
    float mean = stats[o] * inv_n;
    float var = stats[64 + o] * inv_n - mean * mean;
    float rstd = rsqrtf(var + 1e-5f);
    float g = gamma[o] * rstd;
    float bb = beta[o] - mean * g;
    uint4 q = ((const uint4*)preout)[i];
    float4 x0 = ((const float4*)x)[i * 2];
    float4 x1 = ((const float4*)x)[i * 2 + 1];
    float4 r0, r1;
    r0.x = fmaxf(__uint_as_float(q.x << 16) * g + bb, 0.f) + x0.x;
    r0.y = fmaxf(__uint_as_float(q.x & 0xffff0000u) * g + bb, 0.f) + x0.y;
    r0.z = fmaxf(__uint_as_float(q.y << 16) * g + bb, 0.f) + x0.z;
    r0.w = fmaxf(__uint_as_float(q.y & 0xffff0000u) * g + bb, 0.f) + x0.w;
    r1.x = fmaxf(__uint_as_float(q.z << 16) * g + bb, 0.f) + x1.x;
    r1.y = fmaxf(__uint_as_float(q.z & 0xffff0000u) * g + bb, 0.f) + x1.y;
    r1.z = fmaxf(__uint_as_float(q.w << 16) * g + bb, 0.f) + x1.z;
    r1.w = fmaxf(__uint_as_float(q.w & 0xffff0000u) * g + bb, 0.f) + x1.w;
    ((float4*)out)[i * 2] = r0;
    ((float4*)out)[i * 2 + 1] = r1;
}

extern "C" void kernel_launch(void* const* d_in, const int* in_sizes, int n_in,
                              void* d_out, int out_size, void* d_ws, size_t ws_size,
                              hipStream_t stream) {
    const float* x     = (const float*)d_in[0];
    const float* w_off = (const float*)d_in[1];
    const float* b_off = (const float*)d_in[2];
    const float* w     = (const float*)d_in[3];
    const float* gamma = (const float*)d_in[5];
    const float* beta  = (const float*)d_in[6];
    float* out = (float*)d_out;
    char* wsb = (char*)d_ws;

    unsigned short* xT       = (unsigned short*)wsb;                    // 16,777,216 B (fp16)
    float*          om       = (float*)(wsb + 16777216);                // 14,155,776 B
    unsigned short* preout   = (unsigned short*)(wsb + 30932992);       // 16,777,216 B (bf16)
    unsigned short* wApack   = (unsigned short*)(wsb + 47710208);       // 73,728 B (fp16)
    unsigned short* wOffPack = (unsigned short*)(wsb + 47783936);       // 36,864 B (fp16)
    float*          stats    = (float*)(wsb + 47820800);                // 512 B

    hipMemsetAsync(stats, 0, 512, stream);
    prep_weights<<<216, 256, 0, stream>>>(w_off, w, wApack, wOffPack);
    transpose_x<<<2048, 256, 0, stream>>>(x, xT);
    offset_conv<<<2048, 256, 0, stream>>>(xT, wOffPack, b_off, om);
    dcn_main<<<1024, 512, 0, stream>>>(xT, om, wApack, preout, stats);
    bn_finalize<<<4096, 256, 0, stream>>>(stats, gamma, beta, x, preout, out);
}